// Round 11
// baseline (907.698 us; speedup 1.0000x reference)
//
#include <hip/hip_runtime.h>
#include <hip/hip_bf16.h>
#include <hip/hip_fp16.h>
#include <math.h>

// Problem constants
#define BSZ 8
#define LSEQ 4096
#define HDIM 512
#define PDIM 256
#define MROWS (BSZ * LSEQ)        // 32768
#define NDIM 512                  // 2*PDIM
#define CHUNK 32
#define NCHUNK (LSEQ / CHUNK)     // 128
#define LOG2CHUNK 5
#define NFLAG (BSZ * NCHUNK)      // 1024

typedef __attribute__((ext_vector_type(8))) short bf16x8;
typedef __attribute__((ext_vector_type(4))) float f32x4;

// ---------------------------------------------------------------------------
// Weight prep (1024 blocks): [0,512) -> W1T (params inlined, fp32),
// [512,1024) -> W2T.  Blocks 0..3 also zero the scan flags (4 KB).
// ---------------------------------------------------------------------------
__global__ __launch_bounds__(256) void prep_w(
    const float* __restrict__ Lre, const float* __restrict__ Lim,
    const float* __restrict__ logstep,
    const float* __restrict__ Bmat, __hip_bfloat16* __restrict__ W1T,
    const float* __restrict__ Cmat, __hip_bfloat16* __restrict__ W2T,
    int* __restrict__ flags) {
    const int bid = blockIdx.x;
    const int tid = threadIdx.x;
    if (bid < 4) flags[bid * 256 + tid] = 0;   // zero lookback flags
    if (bid < 512) {
        int idx = bid * 256 + tid;   // p*H + h
        int p = idx >> 9, h = idx & 511;
        float step = expf(logstep[p]);
        float lr = Lre[p], li = Lim[p];
        float mag = expf(lr * step);
        float ar = mag * cosf(li * step);
        float ai = mag * sinf(li * step);
        float den = lr * lr + li * li;
        float nr = ar - 1.0f, ni = ai;
        float fr = (nr * lr + ni * li) / den;
        float fi = (ni * lr - nr * li) / den;
        float br = Bmat[(size_t)(p * HDIM + h) * 2 + 0];
        float bi = Bmat[(size_t)(p * HDIM + h) * 2 + 1];
        W1T[(size_t)(2 * p) * HDIM + h]     = __float2bfloat16(fr * br - fi * bi);
        W1T[(size_t)(2 * p + 1) * HDIM + h] = __float2bfloat16(fr * bi + fi * br);
    } else {
        int idx = (bid - 512) * 256 + tid;  // h*P + p
        int h = idx / PDIM, p = idx % PDIM;
        float cr = Cmat[(size_t)(h * PDIM + p) * 2 + 0];
        float ci = Cmat[(size_t)(h * PDIM + p) * 2 + 1];
        W2T[(size_t)h * NDIM + 2 * p]     = __float2bfloat16(2.0f * cr);
        W2T[(size_t)h * NDIM + 2 * p + 1] = __float2bfloat16(-2.0f * ci);
    }
}

// ---------------------------------------------------------------------------
// GEMM1: Bu(fp16) = x(fp32) @ W1T^T  (R8-verbatim).
// ---------------------------------------------------------------------------
__global__ __launch_bounds__(256) void gemm_xw(
    const float* __restrict__ A,            // M x K fp32 (= x)
    const __hip_bfloat16* __restrict__ BT,  // N x K bf16 (= W1T)
    __half* __restrict__ C,                 // M x N fp16 (= Bu)
    int M, int N, int K) {
    __shared__ __hip_bfloat16 smA[2 * 128 * 32];   // 16 KB
    __shared__ __hip_bfloat16 smB[2 * 128 * 32];   // 16 KB

    const int tid = threadIdx.x;
    const int lane = tid & 63;
    const int wave = tid >> 6;            // 0..3
    const int row0 = blockIdx.x * 128;    // row tile fast dim
    const int col0 = blockIdx.y * 128;
    const int wm = (wave >> 1) * 64;
    const int wn = (wave & 1) * 64;

    const int sr = lane >> 2;             // staged row within 16-row chunk
    const int swz_st = ((lane >> 2) & 3) ^ ((lane >> 4) & 3);
    const int sk = (((lane & 3) ^ swz_st) * 8);   // swizzled source k-seg (elems)
    const int quad = lane >> 4;
    const int l15 = lane & 15;
    const int rq = ((quad ^ ((l15 & 3) ^ ((l15 >> 2) & 3))) * 8);

    f32x4 acc[4][4] = {};

    auto stageB = [&](int buf, int t) {
        const int k0 = t << 5;
#pragma unroll
        for (int q = 0; q < 2; ++q) {
            const int chunk = wave * 32 + q * 16;
            const __hip_bfloat16* gB = BT + (size_t)(col0 + chunk + sr) * K + k0 + sk;
            __builtin_amdgcn_global_load_lds(
                (const __attribute__((address_space(1))) void*)gB,
                (__attribute__((address_space(3))) void*)&smB[buf * 4096 + chunk * 32],
                16, 0, 0);
        }
    };
    auto loadA = [&](int t, float4* ar) {
        const int k0 = t << 5;
#pragma unroll
        for (int q = 0; q < 2; ++q) {
            const float* gA = A + (size_t)(row0 + wave * 32 + q * 16 + sr) * K + k0 + sk;
            ar[q * 2]     = *(const float4*)gA;
            ar[q * 2 + 1] = *(const float4*)(gA + 4);
        }
    };
    auto writeA = [&](int buf, const float4* ar) {
#pragma unroll
        for (int q = 0; q < 2; ++q) {
            union { bf16x8 v; __hip_bfloat16 h[8]; } o;
            o.h[0] = __float2bfloat16(ar[q * 2].x);
            o.h[1] = __float2bfloat16(ar[q * 2].y);
            o.h[2] = __float2bfloat16(ar[q * 2].z);
            o.h[3] = __float2bfloat16(ar[q * 2].w);
            o.h[4] = __float2bfloat16(ar[q * 2 + 1].x);
            o.h[5] = __float2bfloat16(ar[q * 2 + 1].y);
            o.h[6] = __float2bfloat16(ar[q * 2 + 1].z);
            o.h[7] = __float2bfloat16(ar[q * 2 + 1].w);
            *(bf16x8*)&smA[buf * 4096 + (wave * 32 + q * 16 + sr) * 32 + (lane & 3) * 8] = o.v;
        }
    };

    const int nk = K >> 5;
    float4 ar[4];
    loadA(0, ar);
    stageB(0, 0);
    writeA(0, ar);
    __syncthreads();

    int buf = 0;
    for (int t = 0; t < nk; ++t) {
        if (t + 1 < nk) {
            loadA(t + 1, ar);
            stageB(buf ^ 1, t + 1);
        }

        const __hip_bfloat16* sA = &smA[buf * 4096];
        const __hip_bfloat16* sB = &smB[buf * 4096];
        bf16x8 af[4], bfr[4];
#pragma unroll
        for (int i = 0; i < 4; ++i)
            af[i] = *(const bf16x8*)&sA[(wm + i * 16 + l15) * 32 + rq];
#pragma unroll
        for (int j = 0; j < 4; ++j)
            bfr[j] = *(const bf16x8*)&sB[(wn + j * 16 + l15) * 32 + rq];
#pragma unroll
        for (int i = 0; i < 4; ++i)
#pragma unroll
            for (int j = 0; j < 4; ++j)
                acc[i][j] = __builtin_amdgcn_mfma_f32_16x16x32_bf16(
                    af[i], bfr[j], acc[i][j], 0, 0, 0);

        if (t + 1 < nk) writeA(buf ^ 1, ar);
        __syncthreads();
        buf ^= 1;
    }

#pragma unroll
    for (int i = 0; i < 4; ++i) {
        const int mbase = row0 + wm + i * 16 + quad * 4;
#pragma unroll
        for (int j = 0; j < 4; ++j) {
            const int col = col0 + wn + j * 16 + l15;
#pragma unroll
            for (int r = 0; r < 4; ++r) {
                const size_t m = (size_t)(mbase + r);
                C[m * N + col] = __half(acc[i][j][r]);
            }
        }
    }
}

// ---------------------------------------------------------------------------
// GEMM2 (R8-verbatim): out = xsb @ W2T^T + D*x (fp32 skip).
// ---------------------------------------------------------------------------
__global__ __launch_bounds__(256) void gemm_bt_skip(
    const __hip_bfloat16* __restrict__ A,   // M x K (xsb)
    const __hip_bfloat16* __restrict__ BT,  // N x K (W2T)
    float* __restrict__ C,                  // M x N
    const float* __restrict__ Dvec,
    const float* __restrict__ Xskip,        // M x N fp32 (= x)
    int M, int N, int K) {
    __shared__ __hip_bfloat16 smA[3 * 128 * 32];   // 24 KB
    __shared__ __hip_bfloat16 smB[3 * 128 * 32];   // 24 KB

    const int tid = threadIdx.x;
    const int lane = tid & 63;
    const int wave = tid >> 6;            // 0..3
    const int row0 = blockIdx.x * 128;    // row tile fast dim
    const int col0 = blockIdx.y * 128;
    const int wm = (wave >> 1) * 64;
    const int wn = (wave & 1) * 64;

    const int sr = lane >> 2;
    const int swz_st = ((lane >> 2) & 3) ^ ((lane >> 4) & 3);
    const int sk = (((lane & 3) ^ swz_st) * 8);
    const int quad = lane >> 4;
    const int l15 = lane & 15;
    const int rq = ((quad ^ ((l15 & 3) ^ ((l15 >> 2) & 3))) * 8);

    f32x4 acc[4][4] = {};

    auto stage = [&](int buf, int t) {
        const int k0 = t << 5;
#pragma unroll
        for (int q = 0; q < 2; ++q) {
            const int chunk = wave * 32 + q * 16;
            const __hip_bfloat16* gA = A + (size_t)(row0 + chunk + sr) * K + k0 + sk;
            __builtin_amdgcn_global_load_lds(
                (const __attribute__((address_space(1))) void*)gA,
                (__attribute__((address_space(3))) void*)&smA[buf * 4096 + chunk * 32],
                16, 0, 0);
            const __hip_bfloat16* gB = BT + (size_t)(col0 + chunk + sr) * K + k0 + sk;
            __builtin_amdgcn_global_load_lds(
                (const __attribute__((address_space(1))) void*)gB,
                (__attribute__((address_space(3))) void*)&smB[buf * 4096 + chunk * 32],
                16, 0, 0);
        }
    };

    const int nk = K >> 5;
    stage(0, 0);
    stage(1, 1);
    asm volatile("s_waitcnt vmcnt(4)" ::: "memory");
    __builtin_amdgcn_s_barrier();

    int cur = 0;
    for (int t = 0; t < nk; ++t) {
        if (t + 2 < nk) {
            int st = cur + 2; if (st >= 3) st -= 3;
            stage(st, t + 2);
        }

        const __hip_bfloat16* sA = &smA[cur * 4096];
        const __hip_bfloat16* sB = &smB[cur * 4096];
        bf16x8 af[4], bfr[4];
#pragma unroll
        for (int i = 0; i < 4; ++i)
            af[i] = *(const bf16x8*)&sA[(wm + i * 16 + l15) * 32 + rq];
#pragma unroll
        for (int j = 0; j < 4; ++j)
            bfr[j] = *(const bf16x8*)&sB[(wn + j * 16 + l15) * 32 + rq];
#pragma unroll
        for (int i = 0; i < 4; ++i)
#pragma unroll
            for (int j = 0; j < 4; ++j)
                acc[i][j] = __builtin_amdgcn_mfma_f32_16x16x32_bf16(
                    af[i], bfr[j], acc[i][j], 0, 0, 0);

        if (t + 1 < nk) {
            if (t + 2 < nk)
                asm volatile("s_waitcnt vmcnt(4)" ::: "memory");
            else
                asm volatile("s_waitcnt vmcnt(0)" ::: "memory");
            __builtin_amdgcn_s_barrier();
        }
        cur += 1; if (cur == 3) cur = 0;
    }

#pragma unroll
    for (int i = 0; i < 4; ++i) {
        const int mbase = row0 + wm + i * 16 + quad * 4;
#pragma unroll
        for (int j = 0; j < 4; ++j) {
            const int col = col0 + wn + j * 16 + l15;
            const float dv = Dvec[col];
#pragma unroll
            for (int r = 0; r < 4; ++r) {
                const size_t m = (size_t)(mbase + r);
                C[m * N + col] = acc[i][j][r] + dv * Xskip[m * N + col];
            }
        }
    }
}

// ---------------------------------------------------------------------------
// SINGLE-PASS SCAN, decoupled lookback, bounded spin + fallback.
// R10 + ONE FIX: the lookback decay starts at al^0 = 1 (was al — that
// over-decayed every carry by one chunk factor; R10 absmax 0.93).
// Carry algebra (verified against R4's two-pass form):
//   E_c = I_{c-1} = sum_{k>=1} al^{k-1} * (S_{c-k} | I_{c-k} terminal)
//   publish I_c = al*E_c + S_c;  re-apply seeds with E_c.
// ---------------------------------------------------------------------------
__global__ __launch_bounds__(256) void scan_one(
    const __half2* __restrict__ Bu2,
    const float* __restrict__ Lre, const float* __restrict__ Lim,
    const float* __restrict__ logstep,
    float2* __restrict__ Sloc, float2* __restrict__ Sincl,
    int* __restrict__ flags,
    ushort2* __restrict__ xsb2) {
    const int bid = blockIdx.x;            // b*NCHUNK + c
    const int b = bid >> 7;
    const int c = bid & (NCHUNK - 1);
    const int p = threadIdx.x;
    const size_t m0 = (size_t)b * LSEQ + (size_t)c * CHUNK;

    // inline fp32 params
    const float step = expf(logstep[p]);
    const float lr = Lre[p], li = Lim[p];
    const float mag = expf(lr * step);
    const float ar = mag * cosf(li * step);
    const float ai = mag * sinf(li * step);
    float alr = ar, ali = ai;              // al = a^CHUNK
#pragma unroll
    for (int i = 0; i < LOG2CHUNK; ++i) {
        float tr = alr * alr - ali * ali;
        float ti = 2.0f * alr * ali;
        alr = tr; ali = ti;
    }

    // ---- load chunk into regs + local scan from zero ----
    unsigned u[CHUNK];
    float sr = 0.0f, si = 0.0f;
#pragma unroll
    for (int j = 0; j < CHUNK; ++j) {
        union { unsigned w; __half2 h; } cv;
        cv.h = Bu2[(m0 + j) * PDIM + p];
        u[j] = cv.w;
        float2 uv = __half22float2(cv.h);
        float nsr = ar * sr - ai * si + uv.x;
        float nsi = ar * si + ai * sr + uv.y;
        sr = nsr; si = nsi;
    }

    // ---- publish local (or inclusive for c==0) ----
    const size_t sidx = (size_t)bid * PDIM + p;
    if (c == 0) {
        Sincl[sidx] = make_float2(sr, si);
    } else {
        Sloc[sidx] = make_float2(sr, si);
    }
    __threadfence();
    __syncthreads();
    if (threadIdx.x == 0)
        __hip_atomic_store(&flags[bid], (c == 0) ? 2 : 1,
                           __ATOMIC_RELEASE, __HIP_MEMORY_SCOPE_AGENT);

    // ---- lookback: exclusive carry E_c (bounded spin + fallback) ----
    float cr = 0.0f, ci = 0.0f;
    if (c > 0) {
        float dr = 1.0f, di = 0.0f;        // decay = al^(k-1)  [THE FIX]
        int k = 1;
        while (true) {
            const int pb = bid - k;
            int f;
            int polls = 0;
            do {
                f = __hip_atomic_load(&flags[pb], __ATOMIC_ACQUIRE,
                                      __HIP_MEMORY_SCOPE_AGENT);
                if (f == 0) {
                    __builtin_amdgcn_s_sleep(8);
                    if (++polls > 4096) break;     // bounded: fall back
                }
            } while (f == 0);
            float2 s;
            if (f == 0) {
                // Fallback: recompute predecessor's local state from Bu.
                const int cc = pb & (NCHUNK - 1);
                const size_t mp = (size_t)b * LSEQ + (size_t)cc * CHUNK;
                float qr = 0.0f, qi = 0.0f;
                for (int j = 0; j < CHUNK; ++j) {
                    float2 uv = __half22float2(Bu2[(mp + j) * PDIM + p]);
                    float nqr = ar * qr - ai * qi + uv.x;
                    float nqi = ar * qi + ai * qr + uv.y;
                    qr = nqr; qi = nqi;
                }
                s = make_float2(qr, qi);
                f = 1;                              // treat as local-only
            } else {
                s = (f == 2 ? Sincl : Sloc)[(size_t)pb * PDIM + p];
            }
            cr += dr * s.x - di * s.y;
            ci += dr * s.y + di * s.x;
            if (f == 2 || k == c) break;
            float tr = dr * alr - di * ali;
            float ti = dr * ali + di * alr;
            dr = tr; di = ti;
            ++k;
        }
        // inclusive = al*carry + local
        Sincl[sidx] = make_float2(alr * cr - ali * ci + sr,
                                  alr * ci + ali * cr + si);
        __threadfence();
        __syncthreads();
        if (threadIdx.x == 0)
            __hip_atomic_store(&flags[bid], 2,
                               __ATOMIC_RELEASE, __HIP_MEMORY_SCOPE_AGENT);
    }

    // ---- re-apply from registers seeded with exclusive carry ----
    float tr = cr, ti = ci;
#pragma unroll
    for (int j = 0; j < CHUNK; ++j) {
        union { unsigned w; __half2 h; } cv;
        cv.w = u[j];
        float2 uv = __half22float2(cv.h);
        float nsr = ar * tr - ai * ti + uv.x;
        float nsi = ar * ti + ai * tr + uv.y;
        tr = nsr; ti = nsi;
        union { ushort2 u2; __hip_bfloat16 h[2]; } o;
        o.h[0] = __float2bfloat16(tr);
        o.h[1] = __float2bfloat16(ti);
        xsb2[(m0 + j) * PDIM + p] = o.u2;
    }
}

// ---------------------------------------------------------------------------
extern "C" void kernel_launch(void* const* d_in, const int* in_sizes, int n_in,
                              void* d_out, int out_size, void* d_ws, size_t ws_size,
                              hipStream_t stream) {
    const float* x       = (const float*)d_in[0];
    const float* Lre     = (const float*)d_in[1];
    const float* Lim     = (const float*)d_in[2];
    const float* Bmat    = (const float*)d_in[3];
    const float* Cmat    = (const float*)d_in[4];
    const float* Dvec    = (const float*)d_in[5];
    const float* logstep = (const float*)d_in[6];
    float* out = (float*)d_out;

    char* ws = (char*)d_ws;
    const size_t MB = 1u << 20;
    __hip_bfloat16* xsb = (__hip_bfloat16*)(ws + 0);         // 32 MB
    __half* Bu          = (__half*)(ws + 32 * MB);           // 32 MB
    __hip_bfloat16* W1T = (__hip_bfloat16*)(ws + 64 * MB);   // 0.5 MB
    __hip_bfloat16* W2T = (__hip_bfloat16*)(ws + 64 * MB + 512 * 1024);
    float2* Sloc  = (float2*)(ws + 66 * MB);                 // 2 MB
    float2* Sincl = (float2*)(ws + 68 * MB);                 // 2 MB
    int*    flags = (int*)(ws + 70 * MB);                    // 4 KB

    // 1. Weight prep (params inlined fp32) + flag zeroing
    prep_w<<<1024, 256, 0, stream>>>(Lre, Lim, logstep, Bmat, W1T, Cmat, W2T, flags);

    // 2. GEMM1: Bu(fp16) = x(fp32) @ W1T^T
    dim3 ggrid(MROWS / 128, NDIM / 128);  // (256, 4), row-fast
    gemm_xw<<<ggrid, 256, 0, stream>>>(x, W1T, Bu, MROWS, NDIM, HDIM);

    // 3. Single-pass scan (bounded-lookback), emits xs as bf16
    scan_one<<<NFLAG, 256, 0, stream>>>((const __half2*)Bu, Lre, Lim, logstep,
                                        Sloc, Sincl, flags, (ushort2*)xsb);

    // 4. GEMM2: out = xsb @ W2T^T + D*x
    dim3 ggrid2(MROWS / 128, HDIM / 128);
    gemm_bt_skip<<<ggrid2, 256, 0, stream>>>(
        xsb, W2T, out, Dvec, x, MROWS, HDIM, NDIM);
}

// Round 12
// 212.407 us; speedup vs baseline: 4.2734x; 4.2734x over previous
//
#include <hip/hip_runtime.h>
#include <hip/hip_bf16.h>
#include <hip/hip_fp16.h>
#include <math.h>

// Problem constants
#define BSZ 8
#define LSEQ 4096
#define HDIM 512
#define PDIM 256
#define MROWS (BSZ * LSEQ)        // 32768
#define NDIM 512                  // 2*PDIM
#define CHUNK 32
#define NCHUNK (LSEQ / CHUNK)     // 128
#define LOG2CHUNK 5

typedef __attribute__((ext_vector_type(8))) short bf16x8;
typedef __attribute__((ext_vector_type(4))) float f32x4;

// Inline fp32 Lambda_bar (R11-proven: passes at absmax 0.0625)
__device__ __forceinline__ void lambda_bar(const float* Lre, const float* Lim,
                                           const float* logstep, int p,
                                           float& ar, float& ai) {
    float step = expf(logstep[p]);
    float lr = Lre[p], li = Lim[p];
    float mag = expf(lr * step);
    ar = mag * cosf(li * step);
    ai = mag * sinf(li * step);
}

// ---------------------------------------------------------------------------
// Weight prep (1024 blocks): [0,512) -> W1T (params inlined, fp32),
// [512,1024) -> W2T.
// ---------------------------------------------------------------------------
__global__ __launch_bounds__(256) void prep_w(
    const float* __restrict__ Lre, const float* __restrict__ Lim,
    const float* __restrict__ logstep,
    const float* __restrict__ Bmat, __hip_bfloat16* __restrict__ W1T,
    const float* __restrict__ Cmat, __hip_bfloat16* __restrict__ W2T) {
    const int bid = blockIdx.x;
    const int tid = threadIdx.x;
    if (bid < 512) {
        int idx = bid * 256 + tid;   // p*H + h
        int p = idx >> 9, h = idx & 511;
        float ar, ai;
        lambda_bar(Lre, Lim, logstep, p, ar, ai);
        float lr = Lre[p], li = Lim[p];
        float den = lr * lr + li * li;
        float nr = ar - 1.0f, ni = ai;
        float fr = (nr * lr + ni * li) / den;
        float fi = (ni * lr - nr * li) / den;
        float br = Bmat[(size_t)(p * HDIM + h) * 2 + 0];
        float bi = Bmat[(size_t)(p * HDIM + h) * 2 + 1];
        W1T[(size_t)(2 * p) * HDIM + h]     = __float2bfloat16(fr * br - fi * bi);
        W1T[(size_t)(2 * p + 1) * HDIM + h] = __float2bfloat16(fr * bi + fi * br);
    } else {
        int idx = (bid - 512) * 256 + tid;  // h*P + p
        int h = idx / PDIM, p = idx % PDIM;
        float cr = Cmat[(size_t)(h * PDIM + p) * 2 + 0];
        float ci = Cmat[(size_t)(h * PDIM + p) * 2 + 1];
        W2T[(size_t)h * NDIM + 2 * p]     = __float2bfloat16(2.0f * cr);
        W2T[(size_t)h * NDIM + 2 * p + 1] = __float2bfloat16(-2.0f * ci);
    }
}

// ---------------------------------------------------------------------------
// GEMM1: Bu(fp16) = x(fp32) @ W1T^T  (R8-verbatim).
// ---------------------------------------------------------------------------
__global__ __launch_bounds__(256) void gemm_xw(
    const float* __restrict__ A,            // M x K fp32 (= x)
    const __hip_bfloat16* __restrict__ BT,  // N x K bf16 (= W1T)
    __half* __restrict__ C,                 // M x N fp16 (= Bu)
    int M, int N, int K) {
    __shared__ __hip_bfloat16 smA[2 * 128 * 32];   // 16 KB
    __shared__ __hip_bfloat16 smB[2 * 128 * 32];   // 16 KB

    const int tid = threadIdx.x;
    const int lane = tid & 63;
    const int wave = tid >> 6;            // 0..3
    const int row0 = blockIdx.x * 128;    // row tile fast dim
    const int col0 = blockIdx.y * 128;
    const int wm = (wave >> 1) * 64;
    const int wn = (wave & 1) * 64;

    const int sr = lane >> 2;             // staged row within 16-row chunk
    const int swz_st = ((lane >> 2) & 3) ^ ((lane >> 4) & 3);
    const int sk = (((lane & 3) ^ swz_st) * 8);   // swizzled source k-seg (elems)
    const int quad = lane >> 4;
    const int l15 = lane & 15;
    const int rq = ((quad ^ ((l15 & 3) ^ ((l15 >> 2) & 3))) * 8);

    f32x4 acc[4][4] = {};

    auto stageB = [&](int buf, int t) {
        const int k0 = t << 5;
#pragma unroll
        for (int q = 0; q < 2; ++q) {
            const int chunk = wave * 32 + q * 16;
            const __hip_bfloat16* gB = BT + (size_t)(col0 + chunk + sr) * K + k0 + sk;
            __builtin_amdgcn_global_load_lds(
                (const __attribute__((address_space(1))) void*)gB,
                (__attribute__((address_space(3))) void*)&smB[buf * 4096 + chunk * 32],
                16, 0, 0);
        }
    };
    auto loadA = [&](int t, float4* ar) {
        const int k0 = t << 5;
#pragma unroll
        for (int q = 0; q < 2; ++q) {
            const float* gA = A + (size_t)(row0 + wave * 32 + q * 16 + sr) * K + k0 + sk;
            ar[q * 2]     = *(const float4*)gA;
            ar[q * 2 + 1] = *(const float4*)(gA + 4);
        }
    };
    auto writeA = [&](int buf, const float4* ar) {
#pragma unroll
        for (int q = 0; q < 2; ++q) {
            union { bf16x8 v; __hip_bfloat16 h[8]; } o;
            o.h[0] = __float2bfloat16(ar[q * 2].x);
            o.h[1] = __float2bfloat16(ar[q * 2].y);
            o.h[2] = __float2bfloat16(ar[q * 2].z);
            o.h[3] = __float2bfloat16(ar[q * 2].w);
            o.h[4] = __float2bfloat16(ar[q * 2 + 1].x);
            o.h[5] = __float2bfloat16(ar[q * 2 + 1].y);
            o.h[6] = __float2bfloat16(ar[q * 2 + 1].z);
            o.h[7] = __float2bfloat16(ar[q * 2 + 1].w);
            *(bf16x8*)&smA[buf * 4096 + (wave * 32 + q * 16 + sr) * 32 + (lane & 3) * 8] = o.v;
        }
    };

    const int nk = K >> 5;
    float4 ar[4];
    loadA(0, ar);
    stageB(0, 0);
    writeA(0, ar);
    __syncthreads();

    int buf = 0;
    for (int t = 0; t < nk; ++t) {
        if (t + 1 < nk) {
            loadA(t + 1, ar);
            stageB(buf ^ 1, t + 1);
        }

        const __hip_bfloat16* sA = &smA[buf * 4096];
        const __hip_bfloat16* sB = &smB[buf * 4096];
        bf16x8 af[4], bfr[4];
#pragma unroll
        for (int i = 0; i < 4; ++i)
            af[i] = *(const bf16x8*)&sA[(wm + i * 16 + l15) * 32 + rq];
#pragma unroll
        for (int j = 0; j < 4; ++j)
            bfr[j] = *(const bf16x8*)&sB[(wn + j * 16 + l15) * 32 + rq];
#pragma unroll
        for (int i = 0; i < 4; ++i)
#pragma unroll
            for (int j = 0; j < 4; ++j)
                acc[i][j] = __builtin_amdgcn_mfma_f32_16x16x32_bf16(
                    af[i], bfr[j], acc[i][j], 0, 0, 0);

        if (t + 1 < nk) writeA(buf ^ 1, ar);
        __syncthreads();
        buf ^= 1;
    }

#pragma unroll
    for (int i = 0; i < 4; ++i) {
        const int mbase = row0 + wm + i * 16 + quad * 4;
#pragma unroll
        for (int j = 0; j < 4; ++j) {
            const int col = col0 + wn + j * 16 + l15;
#pragma unroll
            for (int r = 0; r < 4; ++r) {
                const size_t m = (size_t)(mbase + r);
                C[m * N + col] = __half(acc[i][j][r]);
            }
        }
    }
}

// ---------------------------------------------------------------------------
// GEMM2 (R8-verbatim): out = xsb @ W2T^T + D*x (fp32 skip).
// ---------------------------------------------------------------------------
__global__ __launch_bounds__(256) void gemm_bt_skip(
    const __hip_bfloat16* __restrict__ A,   // M x K (xsb)
    const __hip_bfloat16* __restrict__ BT,  // N x K (W2T)
    float* __restrict__ C,                  // M x N
    const float* __restrict__ Dvec,
    const float* __restrict__ Xskip,        // M x N fp32 (= x)
    int M, int N, int K) {
    __shared__ __hip_bfloat16 smA[3 * 128 * 32];   // 24 KB
    __shared__ __hip_bfloat16 smB[3 * 128 * 32];   // 24 KB

    const int tid = threadIdx.x;
    const int lane = tid & 63;
    const int wave = tid >> 6;            // 0..3
    const int row0 = blockIdx.x * 128;    // row tile fast dim
    const int col0 = blockIdx.y * 128;
    const int wm = (wave >> 1) * 64;
    const int wn = (wave & 1) * 64;

    const int sr = lane >> 2;
    const int swz_st = ((lane >> 2) & 3) ^ ((lane >> 4) & 3);
    const int sk = (((lane & 3) ^ swz_st) * 8);
    const int quad = lane >> 4;
    const int l15 = lane & 15;
    const int rq = ((quad ^ ((l15 & 3) ^ ((l15 >> 2) & 3))) * 8);

    f32x4 acc[4][4] = {};

    auto stage = [&](int buf, int t) {
        const int k0 = t << 5;
#pragma unroll
        for (int q = 0; q < 2; ++q) {
            const int chunk = wave * 32 + q * 16;
            const __hip_bfloat16* gA = A + (size_t)(row0 + chunk + sr) * K + k0 + sk;
            __builtin_amdgcn_global_load_lds(
                (const __attribute__((address_space(1))) void*)gA,
                (__attribute__((address_space(3))) void*)&smA[buf * 4096 + chunk * 32],
                16, 0, 0);
            const __hip_bfloat16* gB = BT + (size_t)(col0 + chunk + sr) * K + k0 + sk;
            __builtin_amdgcn_global_load_lds(
                (const __attribute__((address_space(1))) void*)gB,
                (__attribute__((address_space(3))) void*)&smB[buf * 4096 + chunk * 32],
                16, 0, 0);
        }
    };

    const int nk = K >> 5;
    stage(0, 0);
    stage(1, 1);
    asm volatile("s_waitcnt vmcnt(4)" ::: "memory");
    __builtin_amdgcn_s_barrier();

    int cur = 0;
    for (int t = 0; t < nk; ++t) {
        if (t + 2 < nk) {
            int st = cur + 2; if (st >= 3) st -= 3;
            stage(st, t + 2);
        }

        const __hip_bfloat16* sA = &smA[cur * 4096];
        const __hip_bfloat16* sB = &smB[cur * 4096];
        bf16x8 af[4], bfr[4];
#pragma unroll
        for (int i = 0; i < 4; ++i)
            af[i] = *(const bf16x8*)&sA[(wm + i * 16 + l15) * 32 + rq];
#pragma unroll
        for (int j = 0; j < 4; ++j)
            bfr[j] = *(const bf16x8*)&sB[(wn + j * 16 + l15) * 32 + rq];
#pragma unroll
        for (int i = 0; i < 4; ++i)
#pragma unroll
            for (int j = 0; j < 4; ++j)
                acc[i][j] = __builtin_amdgcn_mfma_f32_16x16x32_bf16(
                    af[i], bfr[j], acc[i][j], 0, 0, 0);

        if (t + 1 < nk) {
            if (t + 2 < nk)
                asm volatile("s_waitcnt vmcnt(4)" ::: "memory");
            else
                asm volatile("s_waitcnt vmcnt(0)" ::: "memory");
            __builtin_amdgcn_s_barrier();
        }
        cur += 1; if (cur == 3) cur = 0;
    }

#pragma unroll
    for (int i = 0; i < 4; ++i) {
        const int mbase = row0 + wm + i * 16 + quad * 4;
#pragma unroll
        for (int j = 0; j < 4; ++j) {
            const int col = col0 + wn + j * 16 + l15;
            const float dv = Dvec[col];
#pragma unroll
            for (int r = 0; r < 4; ++r) {
                const size_t m = (size_t)(mbase + r);
                C[m * N + col] = acc[i][j][r] + dv * Xskip[m * N + col];
            }
        }
    }
}

// ---------------------------------------------------------------------------
// Scan trio (R4-exact structure, params inline fp32).
// ---------------------------------------------------------------------------
__global__ __launch_bounds__(256) void scan_chunks(
    const __half2* __restrict__ Bu2,
    const float* __restrict__ Lre, const float* __restrict__ Lim,
    const float* __restrict__ logstep,
    float2* __restrict__ S) {
    int b = blockIdx.x / NCHUNK;
    int c = blockIdx.x % NCHUNK;
    int p = threadIdx.x;
    float ar, ai;
    lambda_bar(Lre, Lim, logstep, p, ar, ai);
    float sr = 0.0f, si = 0.0f;
    size_t m0 = (size_t)b * LSEQ + (size_t)c * CHUNK;
    for (int j = 0; j < CHUNK; ++j) {
        float2 u = __half22float2(Bu2[(m0 + j) * PDIM + p]);
        float nsr = ar * sr - ai * si + u.x;
        float nsi = ar * si + ai * sr + u.y;
        sr = nsr; si = nsi;
    }
    S[(size_t)(b * NCHUNK + c) * PDIM + p] = make_float2(sr, si);
}

__global__ __launch_bounds__(256) void scan_carry(
    const float2* __restrict__ S,
    const float* __restrict__ Lre, const float* __restrict__ Lim,
    const float* __restrict__ logstep,
    float2* __restrict__ carry) {
    const int wid = blockIdx.x * 4 + (threadIdx.x >> 6);  // 0..2047
    const int b = wid >> 8;        // 0..7
    const int p = wid & 255;       // 0..255
    const int lane = threadIdx.x & 63;
    const int c0 = 2 * lane, c1 = 2 * lane + 1;
    float alr, ali;
    lambda_bar(Lre, Lim, logstep, p, alr, ali);
#pragma unroll
    for (int i = 0; i < LOG2CHUNK; ++i) {   // al = a^CHUNK
        float tr = alr * alr - ali * ali;
        float ti = 2.0f * alr * ali;
        alr = tr; ali = ti;
    }
    float2 s0 = S[(size_t)(b * NCHUNK + c0) * PDIM + p];
    float2 s1 = S[(size_t)(b * NCHUNK + c1) * PDIM + p];
    float Ar = alr * alr - ali * ali;
    float Ai = 2.0f * alr * ali;
    float br = alr * s0.x - ali * s0.y + s1.x;
    float bi = alr * s0.y + ali * s0.x + s1.y;
#pragma unroll
    for (int d = 1; d < 64; d <<= 1) {
        float pAr = __shfl_up(Ar, d);
        float pAi = __shfl_up(Ai, d);
        float pbr = __shfl_up(br, d);
        float pbi = __shfl_up(bi, d);
        if (lane >= d) {
            float nAr = Ar * pAr - Ai * pAi;
            float nAi = Ar * pAi + Ai * pAr;
            float nbr = Ar * pbr - Ai * pbi + br;
            float nbi = Ar * pbi + Ai * pbr + bi;
            Ar = nAr; Ai = nAi; br = nbr; bi = nbi;
        }
    }
    float er = __shfl_up(br, 1);
    float ei = __shfl_up(bi, 1);
    if (lane == 0) { er = 0.0f; ei = 0.0f; }
    carry[(size_t)(b * NCHUNK + c0) * PDIM + p] = make_float2(er, ei);
    carry[(size_t)(b * NCHUNK + c1) * PDIM + p] =
        make_float2(alr * er - ali * ei + s0.x, alr * ei + ali * er + s0.y);
}

__global__ __launch_bounds__(256) void scan_apply(
    const __half2* __restrict__ Bu2,
    const float* __restrict__ Lre, const float* __restrict__ Lim,
    const float* __restrict__ logstep,
    const float2* __restrict__ carry,
    ushort2* __restrict__ xsb2) {
    int b = blockIdx.x / NCHUNK;
    int c = blockIdx.x % NCHUNK;
    int p = threadIdx.x;
    float ar, ai;
    lambda_bar(Lre, Lim, logstep, p, ar, ai);
    float2 c0 = carry[(size_t)(b * NCHUNK + c) * PDIM + p];
    float sr = c0.x, si = c0.y;
    size_t m0 = (size_t)b * LSEQ + (size_t)c * CHUNK;
    for (int j = 0; j < CHUNK; ++j) {
        size_t idx = (m0 + j) * PDIM + p;
        float2 u = __half22float2(Bu2[idx]);
        float nsr = ar * sr - ai * si + u.x;
        float nsi = ar * si + ai * sr + u.y;
        sr = nsr; si = nsi;
        union { ushort2 u2; __hip_bfloat16 h[2]; } o;
        o.h[0] = __float2bfloat16(sr);
        o.h[1] = __float2bfloat16(si);
        xsb2[idx] = o.u2;
    }
}

// ---------------------------------------------------------------------------
extern "C" void kernel_launch(void* const* d_in, const int* in_sizes, int n_in,
                              void* d_out, int out_size, void* d_ws, size_t ws_size,
                              hipStream_t stream) {
    const float* x       = (const float*)d_in[0];
    const float* Lre     = (const float*)d_in[1];
    const float* Lim     = (const float*)d_in[2];
    const float* Bmat    = (const float*)d_in[3];
    const float* Cmat    = (const float*)d_in[4];
    const float* Dvec    = (const float*)d_in[5];
    const float* logstep = (const float*)d_in[6];
    float* out = (float*)d_out;

    char* ws = (char*)d_ws;
    const size_t MB = 1u << 20;
    __hip_bfloat16* xsb = (__hip_bfloat16*)(ws + 0);         // 32 MB
    __half* Bu          = (__half*)(ws + 32 * MB);           // 32 MB
    __hip_bfloat16* W1T = (__hip_bfloat16*)(ws + 64 * MB);   // 0.5 MB
    __hip_bfloat16* W2T = (__hip_bfloat16*)(ws + 64 * MB + 512 * 1024);
    float2* S     = (float2*)(ws + 66 * MB);                 // 1 MB
    float2* carry = (float2*)(ws + 68 * MB);                 // 1 MB

    // 1. Weight prep (params inlined fp32)
    prep_w<<<1024, 256, 0, stream>>>(Lre, Lim, logstep, Bmat, W1T, Cmat, W2T);

    // 2. GEMM1: Bu(fp16) = x(fp32) @ W1T^T
    dim3 ggrid(MROWS / 128, NDIM / 128);  // (256, 4), row-fast
    gemm_xw<<<ggrid, 256, 0, stream>>>(x, W1T, Bu, MROWS, NDIM, HDIM);

    // 3. Scan (R4-exact 3-pass, inline params), emits xs as bf16
    scan_chunks<<<BSZ * NCHUNK, 256, 0, stream>>>((const __half2*)Bu,
                                                  Lre, Lim, logstep, S);
    scan_carry<<<BSZ * PDIM / 4, 256, 0, stream>>>(S, Lre, Lim, logstep, carry);
    scan_apply<<<BSZ * NCHUNK, 256, 0, stream>>>((const __half2*)Bu,
                                                 Lre, Lim, logstep, carry,
                                                 (ushort2*)xsb);

    // 4. GEMM2: out = xsb @ W2T^T + D*x
    dim3 ggrid2(MROWS / 128, HDIM / 128);
    gemm_bt_skip<<<ggrid2, 256, 0, stream>>>(
        xsb, W2T, out, Dvec, x, MROWS, HDIM, NDIM);
}